// Round 11
// baseline (544.806 us; speedup 1.0000x reference)
//
#include <hip/hip_runtime.h>
#include <cstdint>

typedef __fp16 f16x8 __attribute__((ext_vector_type(8)));
typedef __fp16 f16x4 __attribute__((ext_vector_type(4)));
typedef float  f32x4 __attribute__((ext_vector_type(4)));

static constexpr int NDIM = 1024;  // N = H*W = C = KC = VC

// ---------------- workspace layout (bytes) ----------------
static constexpr long long OFF_W     = 0;
static constexpr long long OFF_BIAS  = 6291456;
static constexpr long long OFF_XT    = 6303744;
static constexpr long long OFF_S     = 0;          // St (S^T per batch), overlays W3/xT after proj
static constexpr long long OFF_QKV   = 134217728;  // q|k|v per batch, fp16
// total ws: OFF_QKV + 32*3072*1024*2 = 335,544,320 bytes
// stats scratch lives in d_out (dead until gemm<2> overwrites it):
//   part  = (float2*)d_out          [4 jblocks][32 b][1024 n]  (1 MB)
//   stats = (float2*)d_out + 131072 [32 b][1024 n]             (256 KB)

__device__ __forceinline__ void async16(__fp16* lds, const __fp16* g) {
  __builtin_amdgcn_global_load_lds(
      (const __attribute__((address_space(1))) void*)g,
      (__attribute__((address_space(3))) void*)lds, 16, 0, 0);
}

// ---------------- prep kernels ----------------
__global__ __launch_bounds__(256) void prep_w(const float* __restrict__ Wq,
                                              const float* __restrict__ Wk,
                                              const float* __restrict__ Wv,
                                              const float* __restrict__ bq,
                                              const float* __restrict__ bk,
                                              const float* __restrict__ bv,
                                              __fp16* __restrict__ W3,
                                              float* __restrict__ b3) {
  if (blockIdx.x < 3072) {
    const int i = blockIdx.x * 256 + threadIdx.x;
    const int which = i >> 18;
    const int j = i & 262143;
    const float* src = which == 0 ? Wq : (which == 1 ? Wk : Wv);
    const float4 v = ((const float4*)src)[j];
    f16x4 o = {(__fp16)v.x, (__fp16)v.y, (__fp16)v.z, (__fp16)v.w};
    ((f16x4*)W3)[i] = o;
  } else {
    for (int k = threadIdx.x; k < 3072; k += 256)
      b3[k] = (k < 1024) ? bq[k] : (k < 2048) ? bk[k - 1024] : bv[k - 2048];
  }
}

__global__ __launch_bounds__(256) void transpose_cast_x(const float* __restrict__ x,
                                                        __fp16* __restrict__ xT) {
  __shared__ float t[32][33];
  const int b = blockIdx.z;
  const int n0 = blockIdx.x * 32, c0 = blockIdx.y * 32;
  const float* xb = x + (long long)b * NDIM * NDIM;
  __fp16* ob = xT + (long long)b * NDIM * NDIM;
  const int tx = threadIdx.x & 31, ty = threadIdx.x >> 5;
#pragma unroll
  for (int i = ty; i < 32; i += 8)
    t[i][tx] = xb[(long long)(c0 + i) * NDIM + n0 + tx];
  __syncthreads();
#pragma unroll
  for (int i = ty; i < 32; i += 8)
    ob[(long long)(n0 + i) * NDIM + c0 + tx] = (__fp16)t[tx][i];
}

// ------- 256x256 BK=32 quad-buffered gemm_bt (A[M][K] * B^T[N][K]) -------
// Best verified structure (R4/R10): 4 LDS buffers, ONE barrier + ONE counted
// vmcnt(8) per tile, 16B-slot swizzle slot' = slot ^ ((row>>1)&3) both-sides
// (0 bank conflicts). Tile t reads buf t&3; stages tile t+3 into buf (t+3)&3.
// Publication invariant: vmcnt BEFORE s_barrier.
// EPI 0: fp16 out + bias.  EPI 1: f32 out (St) + per-COLUMN partial softmax
// stats (max, sumexp over the block's 256 rows) -> part[].  EPI 2: residual.

#define STAGE_A(NXT, KN)                                                            \
  async16(&As[(NXT)*8192 + tid*8],        A  + (long long)(m0 + sRow)       * 1024 + (KN) + sCol); \
  async16(&As[(NXT)*8192 + 4096 + tid*8], A  + (long long)(m0 + 128 + sRow) * 1024 + (KN) + sCol);

#define STAGE_B(NXT, KN)                                                            \
  async16(&Bs[(NXT)*8192 + tid*8],        Bp + (long long)(n0 + sRow)       * 1024 + (KN) + sCol); \
  async16(&Bs[(NXT)*8192 + 4096 + tid*8], Bp + (long long)(n0 + 128 + sRow) * 1024 + (KN) + sCol);

#define TILE(BUF, NXT, KN)                                                          \
  asm volatile("s_waitcnt vmcnt(8)" ::: "memory");                                  \
  __builtin_amdgcn_s_barrier();                                                     \
  STAGE_A(NXT, KN)                                                                  \
  STAGE_B(NXT, KN)                                                                  \
  bf[0] = *(const f16x8*)&Bs[(BUF)*8192 + bBase + 0*512];                           \
  bf[1] = *(const f16x8*)&Bs[(BUF)*8192 + bBase + 1*512];                           \
  _Pragma("unroll")                                                                 \
  for (int mf = 0; mf < 8; ++mf)                                                    \
    af[mf] = *(const f16x8*)&As[(BUF)*8192 + aBase + mf*512];                       \
  bf[2] = *(const f16x8*)&Bs[(BUF)*8192 + bBase + 2*512];                           \
  bf[3] = *(const f16x8*)&Bs[(BUF)*8192 + bBase + 3*512];                           \
  _Pragma("unroll")                                                                 \
  for (int mf = 0; mf < 8; ++mf) {                                                  \
    _Pragma("unroll")                                                               \
    for (int nf = 0; nf < 4; ++nf)                                                  \
      acc[mf][nf] = __builtin_amdgcn_mfma_f32_16x16x32_f16(af[mf], bf[nf], acc[mf][nf], 0, 0, 0); \
  }

template <int EPI>
__global__ __launch_bounds__(512, 2)
void gemm256(const __fp16* __restrict__ Ag, const __fp16* __restrict__ Bg,
             void* __restrict__ Cout, const float* __restrict__ bias,
             const float* __restrict__ X, const float* __restrict__ gamma,
             float2* __restrict__ part,
             long long sA, long long sB, long long sC) {
  __shared__ alignas(16) __fp16 As[4 * 8192];
  __shared__ alignas(16) __fp16 Bs[4 * 8192];

  const int tid  = threadIdx.x;
  const int wid  = tid >> 6, lane = tid & 63;
  const int wm   = wid >> 2, wn = wid & 3;       // 2M x 4N, wave tile 128x64
  const int g    = lane >> 4, r = lane & 15;
  const int b    = blockIdx.z;
  const int m0   = blockIdx.y * 256;
  const int n0   = blockIdx.x * 256;

  const __fp16* A  = Ag + (long long)b * sA;
  const __fp16* Bp = Bg + (long long)b * sB;

  // staging source pre-swizzle (LDS dest linear): slot tid&3 of row tid>>2
  // holds source chunk (tid&3) ^ ((row>>1)&3); (row>>1)&3 == (tid>>3)&3.
  const int sRow = tid >> 2;
  const int sCol = ((tid & 3) ^ ((tid >> 3) & 3)) * 8;

  // fragment reads: k-chunk g of row R lives at slot g ^ ((R>>1)&3) = g ^ ((r>>1)&3).
  const int fcol  = (g ^ ((r >> 1) & 3)) * 8;
  const int aBase = (wm * 128 + r) * 32 + fcol;
  const int bBase = (wn * 64 + r) * 32 + fcol;

  f16x8 af[8];
  f16x8 bf[4];
  f32x4 acc[8][4];
#pragma unroll
  for (int i = 0; i < 8; ++i)
#pragma unroll
    for (int j = 0; j < 4; ++j) acc[i][j] = f32x4{0.f, 0.f, 0.f, 0.f};

  // prologue: stage tiles 0,1,2 into bufs 0,1,2
  STAGE_A(0, 0)  STAGE_B(0, 0)
  STAGE_A(1, 32) STAGE_B(1, 32)
  STAGE_A(2, 64) STAGE_B(2, 64)

  for (int t0 = 0; t0 < 1024; t0 += 128) {  // 4 tiles (BK=32) per iteration
    const int ka  = t0 + 96;
    const int k0n = (ka < 1024) ? ka : 0;   // clamped junk prefetch (dead buffer)
    const int k1n = (ka + 32 < 1024) ? ka + 32 : 0;
    const int k2n = (ka + 64 < 1024) ? ka + 64 : 0;
    const int k3n = (ka + 96 < 1024) ? ka + 96 : 0;
    TILE(0, 3, k0n)
    TILE(1, 0, k1n)
    TILE(2, 1, k2n)
    TILE(3, 2, k3n)
  }

  // epilogue: C/D layout col=lane&15, row=(lane>>4)*4+reg
  const float g2 = (EPI == 2) ? gamma[0] : 0.f;
  const int ccol  = n0 + wn * 64 + r;
  const int crow0 = m0 + wm * 128 + g * 4;

  if (EPI == 1) {
    // per-COLUMN partial softmax stats over this block's 256 rows.
    // Thread holds, for each nf, 32 values (8 mf x 4 reg) all in column
    // ccol+nf*16; lanes differing only in g (xor 16,32) share that column.
    asm volatile("s_waitcnt vmcnt(0)" ::: "memory");  // junk stages done before LDS reuse
    __syncthreads();
    float2* LDSp = (float2*)As;  // [256 cols][2 wm]
#pragma unroll
    for (int nf = 0; nf < 4; ++nf) {
      float pm = -3.4e38f;
#pragma unroll
      for (int mf = 0; mf < 8; ++mf)
#pragma unroll
        for (int rg = 0; rg < 4; ++rg) pm = fmaxf(pm, acc[mf][nf][rg]);
      pm = fmaxf(pm, __shfl_xor(pm, 16));
      pm = fmaxf(pm, __shfl_xor(pm, 32));
      float ps = 0.f;
#pragma unroll
      for (int mf = 0; mf < 8; ++mf)
#pragma unroll
        for (int rg = 0; rg < 4; ++rg) ps += __expf(acc[mf][nf][rg] - pm);
      ps += __shfl_xor(ps, 16);
      ps += __shfl_xor(ps, 32);
      if (lane < 16)
        LDSp[(wn * 64 + nf * 16 + r) * 2 + wm] = make_float2(pm, ps);
    }
    __syncthreads();
    if (tid < 256) {
      const float2 a = LDSp[tid * 2 + 0], c2 = LDSp[tid * 2 + 1];
      const float M = fmaxf(a.x, c2.x);
      const float Sv = a.y * __expf(a.x - M) + c2.y * __expf(c2.x - M);
      part[(long long)blockIdx.y * 32768 + b * 1024 + n0 + tid] = make_float2(M, Sv);
    }
  }

#pragma unroll
  for (int mf = 0; mf < 8; ++mf) {
#pragma unroll
    for (int reg = 0; reg < 4; ++reg) {
      const int row = crow0 + mf * 16 + reg;
      const long long rb = (long long)b * sC + (long long)row * 1024;
      const float bb = (EPI == 0) ? bias[row] : 0.f;
#pragma unroll
      for (int nf = 0; nf < 4; ++nf) {
        const int col = ccol + nf * 16;
        const float v = acc[mf][nf][reg];
        if (EPI == 0)      ((__fp16*)Cout)[rb + col] = (__fp16)(v + bb);
        else if (EPI == 1) ((float*)Cout)[rb + col] = v;
        else               ((float*)Cout)[rb + col] = g2 * v + X[rb + col];
      }
    }
  }
}

// ---------------- softmax stats finalize + elementwise ----------------
__global__ __launch_bounds__(256) void finalize_stats(const float2* __restrict__ part,
                                                      float2* __restrict__ stats) {
  const int i = blockIdx.x * 256 + threadIdx.x;  // 32768 = 32 b x 1024 n
  float2 p0 = part[i];
  float2 p1 = part[32768 + i];
  float2 p2 = part[65536 + i];
  float2 p3 = part[98304 + i];
  float M = fmaxf(fmaxf(p0.x, p1.x), fmaxf(p2.x, p3.x));
  float S = p0.y * __expf(p0.x - M) + p1.y * __expf(p1.x - M) +
            p2.y * __expf(p2.x - M) + p3.y * __expf(p3.x - M);
  stats[i] = make_float2(M, 1.f / S);
}

// attnT[b][kk][n] = exp(St[b][kk][n] - m[b][n]) * inv_s[b][n]  (pure streaming)
__global__ __launch_bounds__(256) void softmax_elem(const float* __restrict__ St,
                                                    const float2* __restrict__ stats,
                                                    __fp16* __restrict__ attnT) {
  const long long idx0 = ((long long)blockIdx.x * 256 + threadIdx.x) * 16;
  const int b   = (int)(idx0 >> 20);
  const int rem = (int)(idx0 & 1048575);
  const int n0  = rem & 1023;
  const float4* src = (const float4*)(St + idx0);
  const float2* st  = stats + b * 1024 + n0;
  __fp16* dst = attnT + (long long)b * 3145728 + rem;
  float w[16];
#pragma unroll
  for (int j = 0; j < 4; ++j) {
    const float4 v = src[j];
    const float2 s0 = st[j * 4 + 0], s1 = st[j * 4 + 1], s2 = st[j * 4 + 2], s3 = st[j * 4 + 3];
    w[j * 4 + 0] = __expf(v.x - s0.x) * s0.y;
    w[j * 4 + 1] = __expf(v.y - s1.x) * s1.y;
    w[j * 4 + 2] = __expf(v.z - s2.x) * s2.y;
    w[j * 4 + 3] = __expf(v.w - s3.x) * s3.y;
  }
#pragma unroll
  for (int h = 0; h < 2; ++h) {
    f16x8 o;
#pragma unroll
    for (int e = 0; e < 8; ++e) o[e] = (__fp16)w[h * 8 + e];
    *(f16x8*)(dst + h * 8) = o;
  }
}

// ---------------- launch ----------------
extern "C" void kernel_launch(void* const* d_in, const int* in_sizes, int n_in,
                              void* d_out, int out_size, void* d_ws, size_t ws_size,
                              hipStream_t stream) {
  const float* x     = (const float*)d_in[0];
  const float* Wq    = (const float*)d_in[1];
  const float* bq    = (const float*)d_in[2];
  const float* Wk    = (const float*)d_in[3];
  const float* bk    = (const float*)d_in[4];
  const float* Wv    = (const float*)d_in[5];
  const float* bv    = (const float*)d_in[6];
  const float* gamma = (const float*)d_in[7];
  char* ws = (char*)d_ws;

  __fp16* W3    = (__fp16*)(ws + OFF_W);
  float*  bias3 = (float*)(ws + OFF_BIAS);
  __fp16* xT    = (__fp16*)(ws + OFF_XT);
  float*  St    = (float*)(ws + OFF_S);
  __fp16* QKV   = (__fp16*)(ws + OFF_QKV);
  float*  out   = (float*)d_out;
  float2* part  = (float2*)d_out;            // dead region until gemm<2> writes out
  float2* stats = (float2*)d_out + 131072;   // +1 MB

  prep_w<<<3073, 256, 0, stream>>>(Wq, Wk, Wv, bq, bk, bv, W3, bias3);
  transpose_cast_x<<<dim3(32, 32, 32), 256, 0, stream>>>(x, xT);

  // QKV[b] = W3 (3072x1024) * xT[b]^T  (+bias), fp16
  gemm256<0><<<dim3(4, 12, 32), 512, 0, stream>>>(
      W3, xT, QKV, bias3, nullptr, nullptr, nullptr,
      0LL, 1048576LL, 3145728LL);

  // St[b] = k[b] * q[b]^T  (= S^T), f32; epilogue emits per-column partial stats
  gemm256<1><<<dim3(4, 4, 32), 512, 0, stream>>>(
      QKV + 1048576, QKV, St, nullptr, nullptr, nullptr, part,
      3145728LL, 3145728LL, 1048576LL);

  finalize_stats<<<128, 256, 0, stream>>>(part, stats);
  softmax_elem<<<8192, 256, 0, stream>>>(St, stats, QKV);  // attnT overlays q

  // out[b] = gamma * (v[b] * attnT[b]^T) + x[b], f32 -> d_out
  gemm256<2><<<dim3(4, 4, 32), 512, 0, stream>>>(
      QKV + 2097152, QKV, out, nullptr, x, gamma, nullptr,
      3145728LL, 3145728LL, 1048576LL);
}

// Round 12
// 537.214 us; speedup vs baseline: 1.0141x; 1.0141x over previous
//
#include <hip/hip_runtime.h>
#include <cstdint>

typedef __fp16 f16x8 __attribute__((ext_vector_type(8)));
typedef __fp16 f16x4 __attribute__((ext_vector_type(4)));
typedef float  f32x4 __attribute__((ext_vector_type(4)));

static constexpr int NDIM = 1024;  // N = H*W = C = KC = VC

// ---------------- workspace layout (bytes) ----------------
static constexpr long long OFF_W     = 0;
static constexpr long long OFF_BIAS  = 6291456;
static constexpr long long OFF_XT    = 6303744;
static constexpr long long OFF_S     = 0;          // S f32, overlays W3/xT after proj
static constexpr long long OFF_QKV   = 134217728;  // q|k|v per batch, fp16
// total ws: OFF_QKV + 32*3072*1024*2 = 335,544,320 bytes
// stats scratch lives in d_out (dead until gemm<2> overwrites it):
//   part  = (float2*)d_out          [4 colblocks][32 b][1024 row]  (1 MB)
//   stats = (float2*)d_out + 131072 [32 b][1024 row]               (256 KB)

__device__ __forceinline__ void async16(__fp16* lds, const __fp16* g) {
  __builtin_amdgcn_global_load_lds(
      (const __attribute__((address_space(1))) void*)g,
      (__attribute__((address_space(3))) void*)lds, 16, 0, 0);
}

// ---------------- prep kernels ----------------
__global__ __launch_bounds__(256) void prep_w(const float* __restrict__ Wq,
                                              const float* __restrict__ Wk,
                                              const float* __restrict__ Wv,
                                              const float* __restrict__ bq,
                                              const float* __restrict__ bk,
                                              const float* __restrict__ bv,
                                              __fp16* __restrict__ W3,
                                              float* __restrict__ b3) {
  if (blockIdx.x < 3072) {
    const int i = blockIdx.x * 256 + threadIdx.x;
    const int which = i >> 18;
    const int j = i & 262143;
    const float* src = which == 0 ? Wq : (which == 1 ? Wk : Wv);
    const float4 v = ((const float4*)src)[j];
    f16x4 o = {(__fp16)v.x, (__fp16)v.y, (__fp16)v.z, (__fp16)v.w};
    ((f16x4*)W3)[i] = o;
  } else {
    for (int k = threadIdx.x; k < 3072; k += 256)
      b3[k] = (k < 1024) ? bq[k] : (k < 2048) ? bk[k - 1024] : bv[k - 2048];
  }
}

__global__ __launch_bounds__(256) void transpose_cast_x(const float* __restrict__ x,
                                                        __fp16* __restrict__ xT) {
  __shared__ float t[32][33];
  const int b = blockIdx.z;
  const int n0 = blockIdx.x * 32, c0 = blockIdx.y * 32;
  const float* xb = x + (long long)b * NDIM * NDIM;
  __fp16* ob = xT + (long long)b * NDIM * NDIM;
  const int tx = threadIdx.x & 31, ty = threadIdx.x >> 5;
#pragma unroll
  for (int i = ty; i < 32; i += 8)
    t[i][tx] = xb[(long long)(c0 + i) * NDIM + n0 + tx];
  __syncthreads();
#pragma unroll
  for (int i = ty; i < 32; i += 8)
    ob[(long long)(n0 + i) * NDIM + c0 + tx] = (__fp16)t[tx][i];
}

// ------- 256x256 BK=32 quad-buffered gemm_bt (A[M][K] * B^T[N][K]) -------
// Best verified structure (R4/R10): 4 LDS buffers, ONE barrier + ONE counted
// vmcnt(8) per tile, 16B-slot swizzle slot' = slot ^ ((row>>1)&3) both-sides
// (0 bank conflicts). Tile t reads buf t&3; stages tile t+3 into buf (t+3)&3.
// Publication invariant: vmcnt BEFORE s_barrier.
// EPI 0: fp16 out + bias.  EPI 1: f32 out (S row-major) + per-ROW partial
// softmax stats over the block's 256 cols -> part[].  EPI 2: residual.

#define STAGE_A(NXT, KN)                                                            \
  async16(&As[(NXT)*8192 + tid*8],        A  + (long long)(m0 + sRow)       * 1024 + (KN) + sCol); \
  async16(&As[(NXT)*8192 + 4096 + tid*8], A  + (long long)(m0 + 128 + sRow) * 1024 + (KN) + sCol);

#define STAGE_B(NXT, KN)                                                            \
  async16(&Bs[(NXT)*8192 + tid*8],        Bp + (long long)(n0 + sRow)       * 1024 + (KN) + sCol); \
  async16(&Bs[(NXT)*8192 + 4096 + tid*8], Bp + (long long)(n0 + 128 + sRow) * 1024 + (KN) + sCol);

#define TILE(BUF, NXT, KN)                                                          \
  asm volatile("s_waitcnt vmcnt(8)" ::: "memory");                                  \
  __builtin_amdgcn_s_barrier();                                                     \
  STAGE_A(NXT, KN)                                                                  \
  STAGE_B(NXT, KN)                                                                  \
  bf[0] = *(const f16x8*)&Bs[(BUF)*8192 + bBase + 0*512];                           \
  bf[1] = *(const f16x8*)&Bs[(BUF)*8192 + bBase + 1*512];                           \
  _Pragma("unroll")                                                                 \
  for (int mf = 0; mf < 8; ++mf)                                                    \
    af[mf] = *(const f16x8*)&As[(BUF)*8192 + aBase + mf*512];                       \
  bf[2] = *(const f16x8*)&Bs[(BUF)*8192 + bBase + 2*512];                           \
  bf[3] = *(const f16x8*)&Bs[(BUF)*8192 + bBase + 3*512];                           \
  _Pragma("unroll")                                                                 \
  for (int mf = 0; mf < 8; ++mf) {                                                  \
    _Pragma("unroll")                                                               \
    for (int nf = 0; nf < 4; ++nf)                                                  \
      acc[mf][nf] = __builtin_amdgcn_mfma_f32_16x16x32_f16(af[mf], bf[nf], acc[mf][nf], 0, 0, 0); \
  }

template <int EPI>
__global__ __launch_bounds__(512, 2)
void gemm256(const __fp16* __restrict__ Ag, const __fp16* __restrict__ Bg,
             void* __restrict__ Cout, const float* __restrict__ bias,
             const float* __restrict__ X, const float* __restrict__ gamma,
             float2* __restrict__ part,
             long long sA, long long sB, long long sC) {
  __shared__ alignas(16) __fp16 As[4 * 8192];
  __shared__ alignas(16) __fp16 Bs[4 * 8192];

  const int tid  = threadIdx.x;
  const int wid  = tid >> 6, lane = tid & 63;
  const int wm   = wid >> 2, wn = wid & 3;       // 2M x 4N, wave tile 128x64
  const int g    = lane >> 4, r = lane & 15;
  const int b    = blockIdx.z;
  const int m0   = blockIdx.y * 256;
  const int n0   = blockIdx.x * 256;

  const __fp16* A  = Ag + (long long)b * sA;
  const __fp16* Bp = Bg + (long long)b * sB;

  // staging source pre-swizzle (LDS dest linear): slot tid&3 of row tid>>2
  // holds source chunk (tid&3) ^ ((row>>1)&3); (row>>1)&3 == (tid>>3)&3.
  const int sRow = tid >> 2;
  const int sCol = ((tid & 3) ^ ((tid >> 3) & 3)) * 8;

  // fragment reads: k-chunk g of row R lives at slot g ^ ((R>>1)&3) = g ^ ((r>>1)&3).
  const int fcol  = (g ^ ((r >> 1) & 3)) * 8;
  const int aBase = (wm * 128 + r) * 32 + fcol;
  const int bBase = (wn * 64 + r) * 32 + fcol;

  f16x8 af[8];
  f16x8 bf[4];
  f32x4 acc[8][4];
#pragma unroll
  for (int i = 0; i < 8; ++i)
#pragma unroll
    for (int j = 0; j < 4; ++j) acc[i][j] = f32x4{0.f, 0.f, 0.f, 0.f};

  // prologue: stage tiles 0,1,2 into bufs 0,1,2 (order per tile: A,A,B,B)
  STAGE_A(0, 0)  STAGE_B(0, 0)
  STAGE_A(1, 32) STAGE_B(1, 32)
  STAGE_A(2, 64) STAGE_B(2, 64)

  for (int t0 = 0; t0 < 1024; t0 += 128) {  // 4 tiles (BK=32) per iteration
    const int ka  = t0 + 96;
    const int k0n = (ka < 1024) ? ka : 0;   // clamped junk prefetch (dead buffer)
    const int k1n = (ka + 32 < 1024) ? ka + 32 : 0;
    const int k2n = (ka + 64 < 1024) ? ka + 64 : 0;
    const int k3n = (ka + 96 < 1024) ? ka + 96 : 0;
    TILE(0, 3, k0n)
    TILE(1, 0, k1n)
    TILE(2, 1, k2n)
    TILE(3, 2, k3n)
  }

  // epilogue: C/D layout col=lane&15, row=(lane>>4)*4+reg
  const float g2 = (EPI == 2) ? gamma[0] : 0.f;
  const int ccol  = n0 + wn * 64 + r;
  const int crow0 = m0 + wm * 128 + g * 4;

  if (EPI == 1) {
    // per-ROW partial softmax stats over this block's 256 cols.
    // For each (mf,reg) the thread's 4 nf-values share one row; the 16
    // r-lanes (xor 1,2,4,8) tile the wave's 64-col span of that row.
    asm volatile("s_waitcnt vmcnt(0)" ::: "memory");  // junk stages done before LDS reuse
    __syncthreads();
    float2* LDSp = (float2*)As;  // [256 rows][4 wn]
#pragma unroll
    for (int mf = 0; mf < 8; ++mf) {
#pragma unroll
      for (int reg = 0; reg < 4; ++reg) {
        float M = fmaxf(fmaxf(acc[mf][0][reg], acc[mf][1][reg]),
                        fmaxf(acc[mf][2][reg], acc[mf][3][reg]));
        M = fmaxf(M, __shfl_xor(M, 1));
        M = fmaxf(M, __shfl_xor(M, 2));
        M = fmaxf(M, __shfl_xor(M, 4));
        M = fmaxf(M, __shfl_xor(M, 8));
        float Sv = __expf(acc[mf][0][reg] - M) + __expf(acc[mf][1][reg] - M) +
                   __expf(acc[mf][2][reg] - M) + __expf(acc[mf][3][reg] - M);
        Sv += __shfl_xor(Sv, 1);
        Sv += __shfl_xor(Sv, 2);
        Sv += __shfl_xor(Sv, 4);
        Sv += __shfl_xor(Sv, 8);
        if (r == 0) {
          const int rl = wm * 128 + mf * 16 + g * 4 + reg;
          LDSp[rl * 4 + wn] = make_float2(M, Sv);
        }
      }
    }
    __syncthreads();
    if (tid < 256) {
      const float2 p0 = LDSp[tid * 4 + 0], p1 = LDSp[tid * 4 + 1];
      const float2 p2 = LDSp[tid * 4 + 2], p3 = LDSp[tid * 4 + 3];
      const float M = fmaxf(fmaxf(p0.x, p1.x), fmaxf(p2.x, p3.x));
      const float Sv = p0.y * __expf(p0.x - M) + p1.y * __expf(p1.x - M) +
                       p2.y * __expf(p2.x - M) + p3.y * __expf(p3.x - M);
      part[(long long)blockIdx.x * 32768 + b * 1024 + m0 + tid] = make_float2(M, Sv);
    }
  }

#pragma unroll
  for (int mf = 0; mf < 8; ++mf) {
#pragma unroll
    for (int reg = 0; reg < 4; ++reg) {
      const int row = crow0 + mf * 16 + reg;
      const long long rb = (long long)b * sC + (long long)row * 1024;
      const float bb = (EPI == 0) ? bias[row] : 0.f;
#pragma unroll
      for (int nf = 0; nf < 4; ++nf) {
        const int col = ccol + nf * 16;
        const float v = acc[mf][nf][reg];
        if (EPI == 0)      ((__fp16*)Cout)[rb + col] = (__fp16)(v + bb);
        else if (EPI == 1) ((float*)Cout)[rb + col] = v;
        else               ((float*)Cout)[rb + col] = g2 * v + X[rb + col];
      }
    }
  }
}

// ---------------- stats finalize + softmax/transpose ----------------
__global__ __launch_bounds__(256) void finalize_stats(const float2* __restrict__ part,
                                                      float2* __restrict__ stats) {
  const int i = blockIdx.x * 256 + threadIdx.x;  // 32768 = 32 b x 1024 rows
  float2 p0 = part[i];
  float2 p1 = part[32768 + i];
  float2 p2 = part[65536 + i];
  float2 p3 = part[98304 + i];
  float M = fmaxf(fmaxf(p0.x, p1.x), fmaxf(p2.x, p3.x));
  float S = p0.y * __expf(p0.x - M) + p1.y * __expf(p1.x - M) +
            p2.y * __expf(p2.x - M) + p3.y * __expf(p3.x - M);
  stats[i] = make_float2(M, 1.f / S);
}

// attnT[j][i] = exp(S[i][j]-m[i])/s[i], fp16 (same as R10)
__global__ __launch_bounds__(256) void softmax_transpose(const float* __restrict__ S,
                                                         const float2* __restrict__ stats,
                                                         __fp16* __restrict__ attnT) {
  __shared__ __fp16 t[64][72];
  const int b = blockIdx.z;
  const int i0 = blockIdx.y * 64, j0 = blockIdx.x * 64;
  const float* Sb = S + (long long)b * NDIM * NDIM;
  const float2* st = stats + b * NDIM;
  const int tr = threadIdx.x >> 4;
  const int tc = (threadIdx.x & 15) * 4;
#pragma unroll
  for (int it = 0; it < 4; it++) {
    const int i = tr + 16 * it;
    const float4 vv = *(const float4*)&Sb[(long long)(i0 + i) * NDIM + j0 + tc];
    const float2 ms = st[i0 + i];
    t[tc + 0][i] = (__fp16)(__expf(vv.x - ms.x) * ms.y);
    t[tc + 1][i] = (__fp16)(__expf(vv.y - ms.x) * ms.y);
    t[tc + 2][i] = (__fp16)(__expf(vv.z - ms.x) * ms.y);
    t[tc + 3][i] = (__fp16)(__expf(vv.w - ms.x) * ms.y);
  }
  __syncthreads();
  __fp16* Ab = attnT + (long long)b * 3145728;
#pragma unroll
  for (int it = 0; it < 4; it++) {
    const int j = tr + 16 * it;
    f16x4 o = {t[j][tc], t[j][tc + 1], t[j][tc + 2], t[j][tc + 3]};
    *(f16x4*)&Ab[(long long)(j0 + j) * NDIM + i0 + tc] = o;
  }
}

// ---------------- launch ----------------
extern "C" void kernel_launch(void* const* d_in, const int* in_sizes, int n_in,
                              void* d_out, int out_size, void* d_ws, size_t ws_size,
                              hipStream_t stream) {
  const float* x     = (const float*)d_in[0];
  const float* Wq    = (const float*)d_in[1];
  const float* bq    = (const float*)d_in[2];
  const float* Wk    = (const float*)d_in[3];
  const float* bk    = (const float*)d_in[4];
  const float* Wv    = (const float*)d_in[5];
  const float* bv    = (const float*)d_in[6];
  const float* gamma = (const float*)d_in[7];
  char* ws = (char*)d_ws;

  __fp16* W3    = (__fp16*)(ws + OFF_W);
  float*  bias3 = (float*)(ws + OFF_BIAS);
  __fp16* xT    = (__fp16*)(ws + OFF_XT);
  float*  S     = (float*)(ws + OFF_S);
  __fp16* QKV   = (__fp16*)(ws + OFF_QKV);
  float*  out   = (float*)d_out;
  float2* part  = (float2*)d_out;            // dead region until gemm<2> writes out
  float2* stats = (float2*)d_out + 131072;   // +1 MB

  prep_w<<<3073, 256, 0, stream>>>(Wq, Wk, Wv, bq, bk, bv, W3, bias3);
  transpose_cast_x<<<dim3(32, 32, 32), 256, 0, stream>>>(x, xT);

  // QKV[b] = W3 (3072x1024) * xT[b]^T  (+bias), fp16
  gemm256<0><<<dim3(4, 12, 32), 512, 0, stream>>>(
      W3, xT, QKV, bias3, nullptr, nullptr, nullptr,
      0LL, 1048576LL, 3145728LL);

  // S[b] = q[b] * k[b]^T, f32, row-major; epilogue emits per-row partial stats
  gemm256<1><<<dim3(4, 4, 32), 512, 0, stream>>>(
      QKV, QKV + 1048576, S, nullptr, nullptr, nullptr, part,
      3145728LL, 3145728LL, 1048576LL);

  finalize_stats<<<128, 256, 0, stream>>>(part, stats);
  softmax_transpose<<<dim3(16, 16, 32), 256, 0, stream>>>(S, stats, QKV);  // attnT overlays q

  // out[b] = gamma * (v[b] * attnT[b]^T) + x[b], f32 -> d_out
  gemm256<2><<<dim3(4, 4, 32), 512, 0, stream>>>(
      QKV + 2097152, QKV, out, nullptr, x, gamma, nullptr,
      3145728LL, 3145728LL, 1048576LL);
}